// Round 1
// baseline (314.261 us; speedup 1.0000x reference)
//
#include <hip/hip_runtime.h>
#include <cstdint>
#include <cstddef>

typedef unsigned short u16;
typedef __attribute__((ext_vector_type(4))) float  float4v;
typedef __attribute__((ext_vector_type(4))) int    int4v;
typedef __attribute__((ext_vector_type(8))) short  short8v;
typedef __attribute__((ext_vector_type(4))) short  short4v;

#define L_SEQ 4096
#define NH 16
#define NKV 4
#define WND 1024

static __device__ __forceinline__ u16 f2bf(float f) {
  union { float f; unsigned u; } v; v.f = f;
  unsigned r = (v.u + 0x7FFFu + ((v.u >> 16) & 1u)) >> 16;  // RNE
  return (u16)r;
}
static __device__ __forceinline__ u16 f2bf_fast(float f) {   // round-half-up, 2 ops
  union { float f; unsigned u; } v; v.f = f;
  return (u16)((v.u + 0x8000u) >> 16);
}
static __device__ __forceinline__ float bf2f(u16 b) {
  union { unsigned u; float f; } v; v.u = ((unsigned)b) << 16;
  return v.f;
}

// ---------------- fp32 -> bf16 elementwise (x4 vectorized) ----------------
__global__ __launch_bounds__(256) void k_cvt(const float* __restrict__ in,
                                             u16* __restrict__ out, int n4) {
  int i = blockIdx.x * 256 + threadIdx.x;
  if (i >= n4) return;
  float4v v = ((const float4v*)in)[i];
  short4v o;
  o[0] = (short)f2bf(v[0]); o[1] = (short)f2bf(v[1]);
  o[2] = (short)f2bf(v[2]); o[3] = (short)f2bf(v[3]);
  ((short4v*)out)[i] = o;
}

// --- transpose+convert 64x64: in fp32 [K][N] -> out bf16 [(row_off+n)][K] ---
__global__ __launch_bounds__(256) void k_transpose64(const float* __restrict__ in,
                                                     u16* __restrict__ out,
                                                     int K, int N, int row_off) {
  __shared__ float tile[64][65];
  int n0 = blockIdx.x * 64, k0 = blockIdx.y * 64;
  int tx = threadIdx.x & 63, ty = threadIdx.x >> 6;
#pragma unroll
  for (int i = 0; i < 16; i++)
    tile[ty + i*4][tx] = in[(size_t)(k0 + ty + i*4)*N + n0 + tx];
  __syncthreads();
#pragma unroll
  for (int i = 0; i < 16; i++)
    out[(size_t)(row_off + n0 + ty + i*4)*K + k0 + tx] = f2bf(tile[tx][ty + i*4]);
}

// --- V extract+transpose: qkvb bf16 [L][3072] cols 2560.. -> vT bf16 [512][L] ---
__global__ __launch_bounds__(256) void k_vtrans(const u16* __restrict__ qkvb,
                                                u16* __restrict__ vT) {
  __shared__ u16 tile[64][66];
  int p0 = blockIdx.x * 64, d0 = blockIdx.y * 64;
  int tx = threadIdx.x & 63, ty = threadIdx.x >> 6;
#pragma unroll
  for (int i = 0; i < 16; i++)
    tile[ty + i*4][tx] = qkvb[(size_t)(p0 + ty + i*4)*3072 + 2560 + d0 + tx];
  __syncthreads();
#pragma unroll
  for (int i = 0; i < 16; i++)
    vT[(size_t)(d0 + ty + i*4)*L_SEQ + p0 + tx] = tile[tx][ty + i*4];
}

// ============== 256x256 8-phase bf16 MFMA GEMM (B^T), BK=64 ==============
// m201-style schedule: per K-tile 4 phases {ds_read subtile | stage 1 half-tile
// -> barrier -> lgkmcnt(0) -> 16 MFMA -> barrier}; counted vmcnt(4) once per
// K-tile (phases stage A[t+1]@P0/P1 into idle buffer, B[t+2]@P2/P3 into the
// current buffer's B region whose last read was P1). XOR-swizzled LDS
// (chunk j of row at slot j^(row&7)) -- proven conflict-free in prior rounds.
template<int KDIM>
static __device__ __forceinline__ void stage_half(const u16* __restrict__ g,
                                                  u16* lds, int tid) {
#pragma unroll
  for (int it = 0; it < 2; ++it) {
    int s = it * 512 + tid;
    int row = s >> 3, slot = s & 7;
    __builtin_amdgcn_global_load_lds(
        (const __attribute__((address_space(1))) void*)(g + (size_t)row * KDIM + ((slot ^ (row & 7)) << 3)),
        (__attribute__((address_space(3))) void*)(lds + s * 8), 16, 0, 0);
  }
}

template<int BF16_OUT, int KDIM>
__global__ __launch_bounds__(512, 2) void k_gemm8(const u16* __restrict__ A,
                                                  const u16* __restrict__ B,
                                                  void* __restrict__ Cv,
                                                  int N) {
  constexpr int NT = KDIM >> 6;
  __shared__ alignas(16) u16 As[2][256 * 64];
  __shared__ alignas(16) u16 Bs[2][256 * 64];
  int tid = threadIdx.x;
  int lane = tid & 63, wave = tid >> 6;
  int lr = lane & 15, lg = lane >> 4;
  int wm = (wave >> 2) * 128, wn = (wave & 3) * 64;

  // XCD-aware bijective swizzle (nwg % 8 == 0 for both call sites)
  int nwg = gridDim.x * gridDim.y;
  int orig = blockIdx.y * gridDim.x + blockIdx.x;
  int cpx = nwg >> 3;
  int wg = (orig & 7) * cpx + (orig >> 3);
  int tn = wg % gridDim.x, tm = wg / gridDim.x;
  int m0 = tm * 256, n0 = tn * 256;

  const u16* Ag = A + (size_t)m0 * KDIM;
  const u16* Bg = B + (size_t)n0 * KDIM;

  float4v acc[8][4];
#pragma unroll
  for (int i = 0; i < 8; i++)
#pragma unroll
    for (int j = 0; j < 4; j++)
#pragma unroll
      for (int r = 0; r < 4; r++) acc[i][j][r] = 0.f;

  // ---- prologue: K-tile 0 fully + B halves of K-tile 1 ----
  stage_half<KDIM>(Ag,                          &As[0][0],    tid);
  stage_half<KDIM>(Ag + (size_t)128 * KDIM,     &As[0][8192], tid);
  stage_half<KDIM>(Bg,                          &Bs[0][0],    tid);
  stage_half<KDIM>(Bg + (size_t)128 * KDIM,     &Bs[0][8192], tid);
  stage_half<KDIM>(Bg + 64,                     &Bs[1][0],    tid);
  stage_half<KDIM>(Bg + (size_t)128 * KDIM + 64,&Bs[1][8192], tid);
  asm volatile("s_waitcnt vmcnt(4)" ::: "memory");
  __builtin_amdgcn_s_barrier();

#pragma unroll 2
  for (int t = 0; t < NT; ++t) {
    int cur = t & 1;
    const u16* Asc = &As[cur][0];
    const u16* Bsc = &Bs[cur][0];
    u16* Asn = &As[cur ^ 1][0];
    u16* Bsp = &Bs[cur][0];   // B[t+2] lands back in the current buffer
    short8v a[4][2], b0[2][2], b1[2][2];

    // ---------------- P0: read A(mh0)+B(nh0); stage A0[t+1]; Q(0,0) ----------------
#pragma unroll
    for (int i = 0; i < 4; ++i) {
      int r = wm + i * 16 + lr;
#pragma unroll
      for (int ks = 0; ks < 2; ++ks)
        a[i][ks] = *(const short8v*)(Asc + r * 64 + ((((ks << 2) | lg) ^ (r & 7)) << 3));
    }
#pragma unroll
    for (int j = 0; j < 2; ++j) {
      int r = wn + j * 16 + lr;
#pragma unroll
      for (int ks = 0; ks < 2; ++ks)
        b0[j][ks] = *(const short8v*)(Bsc + r * 64 + ((((ks << 2) | lg) ^ (r & 7)) << 3));
    }
    if (t + 1 < NT)
      stage_half<KDIM>(Ag + (size_t)(t + 1) * 64, Asn, tid);
    __builtin_amdgcn_s_barrier();
    asm volatile("s_waitcnt lgkmcnt(0)" ::: "memory");
    __builtin_amdgcn_sched_barrier(0);
    __builtin_amdgcn_s_setprio(1);
#pragma unroll
    for (int i = 0; i < 4; ++i)
#pragma unroll
      for (int j = 0; j < 2; ++j)
#pragma unroll
        for (int ks = 0; ks < 2; ++ks)
          acc[i][j] = __builtin_amdgcn_mfma_f32_16x16x32_bf16(a[i][ks], b0[j][ks], acc[i][j], 0, 0, 0);
    __builtin_amdgcn_s_setprio(0);
    __builtin_amdgcn_s_barrier();

    // ---------------- P1: read B(nh1); stage A1[t+1]; Q(0,1) ----------------
#pragma unroll
    for (int j = 0; j < 2; ++j) {
      int r = wn + (2 + j) * 16 + lr;
#pragma unroll
      for (int ks = 0; ks < 2; ++ks)
        b1[j][ks] = *(const short8v*)(Bsc + r * 64 + ((((ks << 2) | lg) ^ (r & 7)) << 3));
    }
    if (t + 1 < NT)
      stage_half<KDIM>(Ag + (size_t)128 * KDIM + (size_t)(t + 1) * 64, Asn + 8192, tid);
    __builtin_amdgcn_s_barrier();
    asm volatile("s_waitcnt lgkmcnt(0)" ::: "memory");
    __builtin_amdgcn_sched_barrier(0);
    __builtin_amdgcn_s_setprio(1);
#pragma unroll
    for (int i = 0; i < 4; ++i)
#pragma unroll
      for (int j = 0; j < 2; ++j)
#pragma unroll
        for (int ks = 0; ks < 2; ++ks)
          acc[i][2 + j] = __builtin_amdgcn_mfma_f32_16x16x32_bf16(a[i][ks], b1[j][ks], acc[i][2 + j], 0, 0, 0);
    __builtin_amdgcn_s_setprio(0);
    __builtin_amdgcn_s_barrier();

    // ---------------- P2: read A(mh1); stage B0[t+2]; Q(1,1) ----------------
#pragma unroll
    for (int i = 0; i < 4; ++i) {
      int r = wm + 64 + i * 16 + lr;
#pragma unroll
      for (int ks = 0; ks < 2; ++ks)
        a[i][ks] = *(const short8v*)(Asc + r * 64 + ((((ks << 2) | lg) ^ (r & 7)) << 3));
    }
    if (t + 2 < NT)
      stage_half<KDIM>(Bg + (size_t)(t + 2) * 64, Bsp, tid);
    __builtin_amdgcn_s_barrier();
    asm volatile("s_waitcnt lgkmcnt(0)" ::: "memory");
    __builtin_amdgcn_sched_barrier(0);
    __builtin_amdgcn_s_setprio(1);
#pragma unroll
    for (int i = 0; i < 4; ++i)
#pragma unroll
      for (int j = 0; j < 2; ++j)
#pragma unroll
        for (int ks = 0; ks < 2; ++ks)
          acc[4 + i][2 + j] = __builtin_amdgcn_mfma_f32_16x16x32_bf16(a[i][ks], b1[j][ks], acc[4 + i][2 + j], 0, 0, 0);
    __builtin_amdgcn_s_setprio(0);
    __builtin_amdgcn_s_barrier();

    // ---------------- P3: stage B1[t+2]; vmcnt(4); Q(1,0) ----------------
    if (t + 2 < NT)
      stage_half<KDIM>(Bg + (size_t)128 * KDIM + (size_t)(t + 2) * 64, Bsp + 8192, tid);
    asm volatile("s_waitcnt vmcnt(4)" ::: "memory");
    __builtin_amdgcn_s_barrier();
    __builtin_amdgcn_s_setprio(1);
#pragma unroll
    for (int i = 0; i < 4; ++i)
#pragma unroll
      for (int j = 0; j < 2; ++j)
#pragma unroll
        for (int ks = 0; ks < 2; ++ks)
          acc[4 + i][j] = __builtin_amdgcn_mfma_f32_16x16x32_bf16(a[i][ks], b0[j][ks], acc[4 + i][j], 0, 0, 0);
    __builtin_amdgcn_s_setprio(0);
    __builtin_amdgcn_s_barrier();
  }

#pragma unroll
  for (int mi = 0; mi < 8; ++mi)
#pragma unroll
    for (int ni = 0; ni < 4; ++ni)
#pragma unroll
      for (int r = 0; r < 4; ++r) {
        size_t idx = (size_t)(m0 + wm + mi * 16 + lg * 4 + r) * N + (n0 + wn + ni * 16 + lr);
        if (BF16_OUT) ((u16*)Cv)[idx] = f2bf(acc[mi][ni][r]);
        else          ((float*)Cv)[idx] = acc[mi][ni][r];
      }
}

// ---------------- RMSNorm + RoPE for Q,K ----------------
// Q pre-scaled by HD^-0.5 * log2(e) so attention uses exp2 with no per-score mul.
__global__ __launch_bounds__(256) void k_qknorm(const u16* __restrict__ qkvb,
    const int* __restrict__ positions, const float* __restrict__ q_scale,
    const float* __restrict__ k_scale, u16* __restrict__ qb,
    u16* __restrict__ kb) {
  int p = blockIdx.x * 4 + (threadIdx.x >> 6);
  int l = threadIdx.x & 63;
  const float LOG2_BASE = 13.287712379549449f;
  float ang = (float)positions[p] * exp2f(-(float)l * (LOG2_BASE / 64.0f));
  float sn, cs; sincosf(ang, &sn, &cs);
  float qs1 = q_scale[l], qs2 = q_scale[l + 64];
  float ks1 = k_scale[l], ks2 = k_scale[l + 64];
  const u16* base = qkvb + (size_t)p * 3072;
  const float qsc = 0.12751741505539613f;  // 128^-0.5 * log2(e)
#pragma unroll
  for (int h = 0; h < 16; h++) {
    float x1 = bf2f(base[h*128 + l]), x2 = bf2f(base[h*128 + l + 64]);
    float ss = x1*x1 + x2*x2;
#pragma unroll
    for (int m = 1; m < 64; m <<= 1) ss += __shfl_xor(ss, m);
    float rinv = rsqrtf(ss * (1.0f/128.0f) + 1e-6f);
    x1 *= rinv * qs1; x2 *= rinv * qs2;
    u16* dst = qb + ((size_t)p*NH + h)*128;
    dst[l]      = f2bf((x1*cs - x2*sn) * qsc);
    dst[l + 64] = f2bf((x2*cs + x1*sn) * qsc);
  }
#pragma unroll
  for (int g = 0; g < 4; g++) {
    float x1 = bf2f(base[2048 + g*128 + l]), x2 = bf2f(base[2048 + g*128 + l + 64]);
    float ss = x1*x1 + x2*x2;
#pragma unroll
    for (int m = 1; m < 64; m <<= 1) ss += __shfl_xor(ss, m);
    float rinv = rsqrtf(ss * (1.0f/128.0f) + 1e-6f);
    x1 *= rinv * ks1; x2 *= rinv * ks2;
    u16* dst = kb + ((size_t)p*NKV + g)*128;
    dst[l]      = f2bf(x1*cs - x2*sn);
    dst[l + 64] = f2bf(x2*cs + x1*sn);
  }
}

// ---------------- flash attention v3 ----------------
// XCD-aware block decode: xcd = blockIdx&7 owns one (group, q-half) strip of 64
// consecutive q-tiles -> per-XCD K/V L2 footprint ~1.6 MB (fits 4 MB L2).
// 64-key tiles staged via global_load_lds (XOR-swizzled, conflict-free).
// Fixed-max softmax (RMSNorm bounds |S|); denominator via MFMA against ones.
__global__ __launch_bounds__(256) void k_attn(const u16* __restrict__ qb,
    const u16* __restrict__ kb, const u16* __restrict__ vT,
    u16* __restrict__ ob) {
  __shared__ alignas(16) u16 Ks[64*128];      // [key][dim], chunk c at slot c^(row&15)
  __shared__ alignas(16) u16 Vs[128*64];      // [dim][key], chunk c at slot c^(row&7)
  __shared__ alignas(16) u16 Pw[4][2][16*72]; // per-wave P transpose, pad 64->72
  int tid = threadIdx.x;
  int lane = tid & 63, wave = tid >> 6;
  int lr = lane & 15, lg = lane >> 4;
  int flat = blockIdx.x;
  int xcd = flat & 7, slot = flat >> 3;
  int gh = xcd >> 1;
  int q0 = ((xcd & 1) * 64 + slot) * 32;
  int h = gh * 4 + wave;

  short8v qf[2][4];
#pragma unroll
  for (int m = 0; m < 2; m++) {
    const u16* qrow = qb + ((size_t)(q0 + m*16 + lr)*NH + h)*128 + lg*8;
#pragma unroll
    for (int t = 0; t < 4; t++) qf[m][t] = *(const short8v*)(qrow + t*32);
  }

  const short one_bf = (short)0x3F80;
  const short8v ones = {one_bf,one_bf,one_bf,one_bf,one_bf,one_bf,one_bf,one_bf};

  float4v O[9][2];   // O[8] = P @ ones = softmax denominator
#pragma unroll
  for (int dt = 0; dt < 9; dt++)
#pragma unroll
    for (int m = 0; m < 2; m++)
#pragma unroll
      for (int r = 0; r < 4; r++) O[dt][m][r] = 0.f;

  int kstart = q0 - (WND - 1); if (kstart < 0) kstart = 0; kstart &= ~63;
  for (int kt = kstart; kt < q0 + 32; kt += 64) {
    __syncthreads();
#pragma unroll
    for (int it = 0; it < 4; it++) {
      int s = it*256 + tid;
      { int row = s >> 4, j = s & 15, col = (j ^ (row & 15)) << 3;
        __builtin_amdgcn_global_load_lds(
            (const __attribute__((address_space(1))) void*)(kb + (size_t)(kt + row)*512 + gh*128 + col),
            (__attribute__((address_space(3))) void*)(&Ks[s * 8]), 16, 0, 0); }
      { int row = s >> 3, j = s & 7, col = (j ^ (row & 7)) << 3;
        __builtin_amdgcn_global_load_lds(
            (const __attribute__((address_space(1))) void*)(vT + (size_t)(gh*128 + row)*L_SEQ + kt + col),
            (__attribute__((address_space(3))) void*)(&Vs[s * 8]), 16, 0, 0); }
    }
    __syncthreads();

    float4v S[2][4];
#pragma unroll
    for (int m = 0; m < 2; m++)
#pragma unroll
      for (int t2 = 0; t2 < 4; t2++)
#pragma unroll
        for (int r = 0; r < 4; r++) S[m][t2][r] = 0.f;
#pragma unroll
    for (int t2 = 0; t2 < 4; t2++) {
      int row = t2*16 + lr;
#pragma unroll
      for (int t = 0; t < 4; t++) {
        short8v kf = *(const short8v*)(&Ks[row*128 + (((t*4 + lg) ^ (row & 15)) << 3)]);
        S[0][t2] = __builtin_amdgcn_mfma_f32_16x16x32_bf16(qf[0][t], kf, S[0][t2], 0, 0, 0);
        S[1][t2] = __builtin_amdgcn_mfma_f32_16x16x32_bf16(qf[1][t], kf, S[1][t2], 0, 0, 0);
      }
    }

    // P = exp2(S) with masking only on boundary tiles
    bool need_mask = (kt + 64 > q0) || (kt < q0 - (WND - 32));
    if (need_mask) {
#pragma unroll
      for (int m = 0; m < 2; m++)
#pragma unroll
        for (int r = 0; r < 4; r++) {
          int pos = q0 + m*16 + lg*4 + r;
#pragma unroll
          for (int t2 = 0; t2 < 4; t2++) {
            int key = kt + t2*16 + lr;
            float p = (key > pos || key < pos - (WND - 1)) ? 0.f : exp2f(S[m][t2][r]);
            Pw[wave][m][(lg*4 + r)*72 + t2*16 + lr] = f2bf_fast(p);
          }
        }
    } else {
#pragma unroll
      for (int m = 0; m < 2; m++)
#pragma unroll
        for (int r = 0; r < 4; r++)
#pragma unroll
          for (int t2 = 0; t2 < 4; t2++)
            Pw[wave][m][(lg*4 + r)*72 + t2*16 + lr] = f2bf_fast(exp2f(S[m][t2][r]));
    }

    short8v pf[2][2];
#pragma unroll
    for (int m = 0; m < 2; m++)
#pragma unroll
      for (int sub = 0; sub < 2; sub++)
        pf[m][sub] = *(const short8v*)(&Pw[wave][m][lr*72 + sub*32 + lg*8]);

#pragma unroll
    for (int sub = 0; sub < 2; sub++)
#pragma unroll
      for (int dt = 0; dt < 8; dt++) {
        int row = dt*16 + lr;
        short8v vf = *(const short8v*)(&Vs[row*64 + (((sub*4 + lg) ^ (row & 7)) << 3)]);
        O[dt][0] = __builtin_amdgcn_mfma_f32_16x16x32_bf16(pf[0][sub], vf, O[dt][0], 0, 0, 0);
        O[dt][1] = __builtin_amdgcn_mfma_f32_16x16x32_bf16(pf[1][sub], vf, O[dt][1], 0, 0, 0);
      }
#pragma unroll
    for (int m = 0; m < 2; m++) {
      O[8][m] = __builtin_amdgcn_mfma_f32_16x16x32_bf16(pf[m][0], ones, O[8][m], 0, 0, 0);
      O[8][m] = __builtin_amdgcn_mfma_f32_16x16x32_bf16(pf[m][1], ones, O[8][m], 0, 0, 0);
    }
  }

#pragma unroll
  for (int m = 0; m < 2; m++)
#pragma unroll
    for (int r = 0; r < 4; r++) {
      float inv = 1.0f / O[8][m][r];   // denominator already lane-resident (col-broadcast)
#pragma unroll
      for (int dt = 0; dt < 8; dt++)
        ob[((size_t)(q0 + m*16 + lg*4 + r)*NH + h)*128 + dt*16 + lr] =
            f2bf(O[dt][m][r] * inv);
    }
}

extern "C" void kernel_launch(void* const* d_in, const int* in_sizes, int n_in,
                              void* d_out, int out_size, void* d_ws, size_t ws_size,
                              hipStream_t stream) {
  (void)in_sizes; (void)n_in; (void)out_size; (void)ws_size;
  const float* x        = (const float*)d_in[0];
  const int*   positions= (const int*)d_in[1];
  const float* Wq       = (const float*)d_in[2];
  const float* Wk       = (const float*)d_in[3];
  const float* Wv       = (const float*)d_in[4];
  const float* Wo       = (const float*)d_in[5];
  const float* q_scale  = (const float*)d_in[6];
  const float* k_scale  = (const float*)d_in[7];
  float* out = (float*)d_out;

  char* ws = (char*)d_ws;
  u16* xb   = (u16*)ws; ws += (size_t)4096*2048*2;
  u16* Wt   = (u16*)ws; ws += (size_t)3072*2048*2;
  u16* Wot  = (u16*)ws; ws += (size_t)2048*2048*2;
  u16* qkvb = (u16*)ws; ws += (size_t)4096*3072*2;
  u16* qb   = (u16*)ws; ws += (size_t)4096*2048*2;
  u16* kb   = (u16*)ws; ws += (size_t)4096*512*2;
  u16* vT   = (u16*)ws; ws += (size_t)4096*512*2;
  u16* ob   = qkvb;

  k_cvt<<<8192, 256, 0, stream>>>(x, xb, 2097152);
  k_transpose64<<<dim3(32,32), 256, 0, stream>>>(Wq, Wt, 2048, 2048, 0);
  k_transpose64<<<dim3(8,32),  256, 0, stream>>>(Wk, Wt, 2048, 512, 2048);
  k_transpose64<<<dim3(8,32),  256, 0, stream>>>(Wv, Wt, 2048, 512, 2560);
  k_transpose64<<<dim3(32,32), 256, 0, stream>>>(Wo, Wot, 2048, 2048, 0);
  k_gemm8<1, 2048><<<dim3(12,16), 512, 0, stream>>>(xb, Wt, qkvb, 3072);
  k_qknorm<<<1024, 256, 0, stream>>>(qkvb, positions, q_scale, k_scale, qb, kb);
  k_vtrans<<<dim3(64,8), 256, 0, stream>>>(qkvb, vT);
  k_attn<<<512, 256, 0, stream>>>(qb, kb, vT, ob);
  k_gemm8<0, 2048><<<dim3(8,16), 512, 0, stream>>>(ob, Wot, out, 2048);
}